// Round 13
// baseline (187.404 us; speedup 1.0000x reference)
//
#include <hip/hip_runtime.h>
#include <cstdint>

typedef __attribute__((ext_vector_type(8))) short short8;      // 8 bf16 = 4 VGPRs
typedef __attribute__((ext_vector_type(4))) float floatx4;     // MFMA C/D frag
typedef __attribute__((ext_vector_type(4))) _Float16 half4;    // 16x16x16 f16 A/B frag

#define DEV __device__ __forceinline__

constexpr int NB = 2, Lseq = 2048, NH = 16, HD = 64, EMB = 1024;
// fold softmax scale (1/sqrt(1024)) and log2(e) into Wq so flash uses exp2
constexpr float QSCALE = 0.03125f * 1.4426950408889634f;

DEV uint16_t f2bf(float f) {  // round-to-nearest-even f32 -> bf16
  uint32_t x = __builtin_bit_cast(uint32_t, f);
  x += 0x7fffu + ((x >> 16) & 1u);
  return (uint16_t)(x >> 16);
}

// pack two f32 -> two bf16 in one dword (round-half-up via bias, then v_perm)
DEV uint32_t pack2(float lo, float hi) {
  uint32_t a = __builtin_bit_cast(uint32_t, lo) + 0x8000u;
  uint32_t b = __builtin_bit_cast(uint32_t, hi) + 0x8000u;
  return __builtin_amdgcn_perm(b, a, 0x07060302);
}

DEV uint32_t packh2(float lo, float hi) {  // two f32 -> packed f16 dword
  return __builtin_bit_cast(uint32_t, __builtin_amdgcn_cvt_pkrtz(lo, hi));
}

DEV void gl_lds16(const void* g, void* l) {  // async global->LDS, 16B/lane
  __builtin_amdgcn_global_load_lds((const __attribute__((address_space(1))) void*)g,
                                   (__attribute__((address_space(3))) void*)l, 16, 0, 0);
}

// load 8 consecutive f32, scale, convert to a bf16 MFMA frag chunk
DEV short8 ld8bf(const float* p, float sc) {
  float4 u = *(const float4*)p;
  float4 v = *(const float4*)(p + 4);
  union { short8 s; uint32_t d[4]; } r;
  r.d[0] = pack2(u.x * sc, u.y * sc);
  r.d[1] = pack2(u.z * sc, u.w * sc);
  r.d[2] = pack2(v.x * sc, v.y * sc);
  r.d[3] = pack2(v.z * sc, v.w * sc);
  return r.s;
}

// ---------------- prep: Q/K/V projections (MFMA, LDS-free) + Wout cvt ----------------
__global__ __launch_bounds__(256) void prep_kernel(
    const float* __restrict__ values, const float* __restrict__ keysrc,
    const float* __restrict__ query, const float* __restrict__ Wv,
    const float* __restrict__ Wk, const float* __restrict__ Wq,
    const float* __restrict__ Wout,
    uint16_t* __restrict__ qp, uint16_t* __restrict__ kp,
    uint16_t* __restrict__ vp, uint16_t* __restrict__ wbf) {
  const int t = threadIdx.x, w = t >> 6, lane = t & 63;
  const int quad = lane >> 4, l16 = lane & 15;
  const int wid = blockIdx.x * 4 + w;
  const int mat = wid >> 10, sub = wid & 1023;

  if (mat == 3) {  // Wout f32 -> bf16
#pragma unroll
    for (int i = 0; i < 4; ++i) {
      int idx = sub * 256 + i * 64 + lane;
      float4 v = ((const float4*)Wout)[idx];
      uint2 p;
      p.x = pack2(v.x, v.y);
      p.y = pack2(v.z, v.w);
      ((uint2*)wbf)[idx] = p;
    }
    return;
  }

  floatx4 c[4][4];
#pragma unroll
  for (int i = 0; i < 4; ++i)
#pragma unroll
    for (int j = 0; j < 4; ++j) c[i][j] = floatx4{0.f, 0.f, 0.f, 0.f};

  if (mat < 2) {
    // Q/K: A = W rows (m=e), B = x rows (n=r) -> D[e][r]; lane holds 4 consecutive e.
    const float* src = mat ? keysrc : query;
    const float* W   = mat ? Wk : Wq;
    const float asc  = mat ? 1.f : QSCALE;
    uint16_t* dst    = mat ? kp : qp;
    const int R0 = sub * 64;
    short8 a[4][2], b[4][2];
#pragma unroll
    for (int dc = 0; dc < 2; ++dc) {
#pragma unroll
      for (int f = 0; f < 4; ++f) {
        a[f][dc] = ld8bf(W + (size_t)(f * 16 + l16) * 64 + dc * 32 + quad * 8, asc);
        b[f][dc] = ld8bf(src + (size_t)(R0 + f * 16 + l16) * 64 + dc * 32 + quad * 8, 1.f);
      }
    }
#pragma unroll
    for (int dc = 0; dc < 2; ++dc)
#pragma unroll
      for (int mf = 0; mf < 4; ++mf)
#pragma unroll
        for (int nf = 0; nf < 4; ++nf)
          c[mf][nf] = __builtin_amdgcn_mfma_f32_16x16x32_bf16(a[mf][dc], b[nf][dc], c[mf][nf], 0, 0, 0);
#pragma unroll
    for (int nf = 0; nf < 4; ++nf) {
      int r = R0 + nf * 16 + l16;
      int h = r & 15, l = (r >> 4) & 2047, n = r >> 15;
      uint16_t* drow = dst + ((size_t)(n * 16 + h) * 2048 + l) * 64;
#pragma unroll
      for (int mf = 0; mf < 4; ++mf) {
        uint2 pk;
        pk.x = pack2(c[mf][nf][0], c[mf][nf][1]);
        pk.y = pack2(c[mf][nf][2], c[mf][nf][3]);
        *(uint2*)(drow + mf * 16 + quad * 4) = pk;
      }
    }
  } else {
    // V^T: A = x rows (m=l), B = Wv rows (n=d) -> D[l][d]; vp[nh][d][l] in f16.
    const int nh = sub >> 5, L0 = (sub & 31) * 64;
    const int n = nh >> 4, h = nh & 15;
    short8 a[4][2], b[4][2];
#pragma unroll
    for (int dc = 0; dc < 2; ++dc) {
#pragma unroll
      for (int f = 0; f < 4; ++f) {
        a[f][dc] = ld8bf(values + (size_t)(n * 2048 + L0 + f * 16 + l16) * 1024 + h * 64 + dc * 32 + quad * 8, 1.f);
        b[f][dc] = ld8bf(Wv + (size_t)(f * 16 + l16) * 64 + dc * 32 + quad * 8, 1.f);
      }
    }
#pragma unroll
    for (int dc = 0; dc < 2; ++dc)
#pragma unroll
      for (int mf = 0; mf < 4; ++mf)
#pragma unroll
        for (int nf = 0; nf < 4; ++nf)
          c[mf][nf] = __builtin_amdgcn_mfma_f32_16x16x32_bf16(a[mf][dc], b[nf][dc], c[mf][nf], 0, 0, 0);
#pragma unroll
    for (int nf = 0; nf < 4; ++nf) {
      int d = nf * 16 + l16;
      uint16_t* drow = vp + ((size_t)nh * 64 + d) * 2048 + L0;
#pragma unroll
      for (int mf = 0; mf < 4; ++mf) {
        uint2 pk;
        pk.x = packh2(c[mf][nf][0], c[mf][nf][1]);
        pk.y = packh2(c[mf][nf][2], c[mf][nf][3]);
        *(uint2*)(drow + mf * 16 + quad * 4) = pk;
      }
    }
  }
}

// ---------------- Flash attention: key-split across waves (4x fewer LDS reads) -------
// Block = 64 queries x all keys. Each wave holds ALL 64 queries in registers (bq, o)
// and consumes only ITS 16-key slice of each staged 64-key tile: 2 ds_read_b128 (K)
// + 4 ds_read_b64 (V) per wave-iter vs 8+16 when waves split queries — the K/V frags
// don't depend on the query subset, so query-split waves read 4x redundantly.
// m==0 makes key-partials linear: waves' partial O / l combine once at the end via a
// one-time LDS round-trip. Staging/dbuf/grid/XCD mapping identical to R12.
__global__ __launch_bounds__(256, 2) void flash_kernel(const uint16_t* __restrict__ qp,
                                                       const uint16_t* __restrict__ kp,
                                                       const uint16_t* __restrict__ vp,
                                                       uint16_t* __restrict__ xatt) {
  constexpr int kbn = 32;
  __shared__ uint16_t Kt[2][64 * 64];    // swizzled [key][d] bf16
  __shared__ uint16_t Vt[2][64 * 64];    // swizzled [d][key] f16
  __shared__ float cmb[4][1024];         // per-wave partial-O combine (one db chunk)
  __shared__ float lfb[4][64];           // per-wave partial-l
  const int t = threadIdx.x;
  const int w = t >> 6, lane = t & 63, quad = lane >> 4, l16 = lane & 15;
  const int nh = blockIdx.x, qt = blockIdx.y;
  const int q0 = qt * 64;
  const uint16_t* Qb = qp + (size_t)nh * Lseq * HD;
  const uint16_t* Kb = kp + (size_t)nh * Lseq * HD;
  const uint16_t* Vb = vp + (size_t)nh * HD * Lseq;
  const int srow = lane >> 3, sc8 = (lane & 7) ^ (lane >> 3);  // staging swizzle

  // all 64 queries as B-frags: bq[qb][dc], lane holds Q[q=qb*16+l16][d=quad*8+j]
  short8 bq[4][2];
#pragma unroll
  for (int qb = 0; qb < 4; ++qb) {
    bq[qb][0] = *(const short8*)(Qb + (q0 + qb * 16 + l16) * 64 + quad * 8);
    bq[qb][1] = *(const short8*)(Qb + (q0 + qb * 16 + l16) * 64 + 32 + quad * 8);
  }

  floatx4 o[4][4];   // partial O^T (this wave's keys): [db][qb], row=d, col=q=l16
  floatx4 lfr[4];    // partial l via ones-MFMA, per qb
#pragma unroll
  for (int i = 0; i < 4; ++i) {
    lfr[i] = floatx4{0.f, 0.f, 0.f, 0.f};
#pragma unroll
    for (int j = 0; j < 4; ++j) o[i][j] = floatx4{0.f, 0.f, 0.f, 0.f};
  }
  const _Float16 one = (_Float16)1.0f;
  const half4 vone = {one, one, one, one};

#pragma unroll
  for (int i = 0; i < 2; ++i) {
    int r0 = w * 16 + i * 8;
    gl_lds16(Kb + (r0 + srow) * 64 + sc8 * 8, &Kt[0][r0 * 64]);
    gl_lds16(Vb + (size_t)(r0 + srow) * Lseq + sc8 * 8, &Vt[0][r0 * 64]);
  }

  const int krow = w * 16 + l16;          // this wave's K row for S (key = w*16+l16)
  const int kch0 = w * 2;                 // V chunk base for this wave's 16 keys

  for (int kb = 0; kb < kbn; ++kb) {
    __syncthreads();  // drains DMA for kb (issued one iteration ago)
    const int cur = kb & 1;
    if (kb + 1 < kbn) {
      const int nxt = cur ^ 1;
      const uint16_t* kg = Kb + (kb + 1) * (64 * 64);
#pragma unroll
      for (int i = 0; i < 2; ++i) {
        int r0 = w * 16 + i * 8;
        gl_lds16(kg + (r0 + srow) * 64 + sc8 * 8, &Kt[nxt][r0 * 64]);
        gl_lds16(Vb + (size_t)(r0 + srow) * Lseq + (kb + 1) * 64 + sc8 * 8, &Vt[nxt][r0 * 64]);
      }
    }

    // S^T = K Q^T for this wave's 16 keys x 64 queries: 2 K-frag reads total
    floatx4 s[4];
#pragma unroll
    for (int qb = 0; qb < 4; ++qb) s[qb] = floatx4{0.f, 0.f, 0.f, 0.f};
#pragma unroll
    for (int dc = 0; dc < 2; ++dc) {
      short8 ak = *(const short8*)(&Kt[cur][krow * 64 + ((dc * 4 + quad) ^ (krow & 7)) * 8]);
#pragma unroll
      for (int qb = 0; qb < 4; ++qb)
        s[qb] = __builtin_amdgcn_mfma_f32_16x16x32_bf16(ak, bq[qb][dc], s[qb], 0, 0, 0);
    }

    // p = exp2(s) packed to f16 B-frags (key=quad*4+r matches B[k][n] layout)
    half4 bp[4];
#pragma unroll
    for (int qb = 0; qb < 4; ++qb) {
      float p0 = __builtin_amdgcn_exp2f(s[qb][0]);
      float p1 = __builtin_amdgcn_exp2f(s[qb][1]);
      float p2 = __builtin_amdgcn_exp2f(s[qb][2]);
      float p3 = __builtin_amdgcn_exp2f(s[qb][3]);
      union { half4 h4; uint32_t d[2]; } u;
      u.d[0] = packh2(p0, p1);
      u.d[1] = packh2(p2, p3);
      bp[qb] = u.h4;
      lfr[qb] = __builtin_amdgcn_mfma_f32_16x16x16f16(vone, bp[qb], lfr[qb], 0, 0, 0);
    }

    // O^T += V^T P over this wave's 16 keys: 4 V-frag reads total
#pragma unroll
    for (int db = 0; db < 4; ++db) {
      int row = db * 16 + l16;
      int ch = (kch0 + (quad >> 1)) ^ (row & 7);
      half4 av = *(const half4*)(&Vt[cur][row * 64 + ch * 8 + (quad & 1) * 4]);
#pragma unroll
      for (int qb = 0; qb < 4; ++qb)
        o[db][qb] = __builtin_amdgcn_mfma_f32_16x16x16f16(av, bp[qb], o[db][qb], 0, 0, 0);
    }
  }

  // publish partial l (all lfr rows equal the column sum; col = this lane's query)
  if (quad == 0) {
#pragma unroll
    for (int qb = 0; qb < 4; ++qb) lfb[w][qb * 16 + l16] = lfr[qb][0];
  }

  // cross-wave combine, one db chunk at a time through 16KB of LDS
  const int n = nh >> 4, h = nh & 15;
  const int cq = t >> 2, cd = (t & 3) * 4;   // reader: query cq, d-offset cd
#pragma unroll
  for (int db = 0; db < 4; ++db) {
    __syncthreads();  // db==0: lfb visible + K-loop done; else: prev readers done
#pragma unroll
    for (int qb = 0; qb < 4; ++qb)
      *(floatx4*)(&cmb[w][(qb * 16 + l16) * 16 + quad * 4]) = o[db][qb];
    __syncthreads();
    floatx4 a0 = *(const floatx4*)(&cmb[0][cq * 16 + cd]);
    floatx4 a1 = *(const floatx4*)(&cmb[1][cq * 16 + cd]);
    floatx4 a2 = *(const floatx4*)(&cmb[2][cq * 16 + cd]);
    floatx4 a3 = *(const floatx4*)(&cmb[3][cq * 16 + cd]);
    float inv = __builtin_amdgcn_rcpf(lfb[0][cq] + lfb[1][cq] + lfb[2][cq] + lfb[3][cq]);
    float v0 = (a0[0] + a1[0] + a2[0] + a3[0]) * inv;
    float v1 = (a0[1] + a1[1] + a2[1] + a3[1]) * inv;
    float v2 = (a0[2] + a1[2] + a2[2] + a3[2]) * inv;
    float v3 = (a0[3] + a1[3] + a2[3] + a3[3]) * inv;
    uint2 pk;
    pk.x = pack2(v0, v1);
    pk.y = pack2(v2, v3);
    *(uint2*)(xatt + (size_t)(n * Lseq + q0 + cq) * EMB + h * 64 + db * 16 + cd) = pk;
  }
}

// ---------------- out = X @ Wout^T + bout, 64x128 tile, all-bf16, dbuf DMA ------------
// (unchanged from R12)
__global__ __launch_bounds__(256, 2) void gemm_xat(const uint16_t* __restrict__ X,
                                                   const uint16_t* __restrict__ Wb,
                                                   const float* __restrict__ bias,
                                                   float* __restrict__ out) {
  __shared__ uint16_t Xt[2][64 * 64];
  __shared__ uint16_t Wt[2][128 * 64];
  const int t = threadIdx.x, w = t >> 6, lane = t & 63, quad = lane >> 4, l16 = lane & 15;
  const int m0 = blockIdx.x * 64, o0 = blockIdx.y * 128;
  const int srow = lane >> 3, sc8 = (lane & 7) ^ (lane >> 3);

  floatx4 acc[8];
#pragma unroll
  for (int j = 0; j < 8; ++j) acc[j] = floatx4{0.f, 0.f, 0.f, 0.f};

  auto dma = [&](int buf, int kt) {
    const int e0 = kt * 64;
#pragma unroll
    for (int i = 0; i < 2; ++i) {
      int r0 = w * 16 + i * 8;
      gl_lds16(X + (size_t)(m0 + r0 + srow) * 1024 + e0 + sc8 * 8, &Xt[buf][r0 * 64]);
    }
#pragma unroll
    for (int i = 0; i < 4; ++i) {
      int r0 = w * 32 + i * 8;
      gl_lds16(Wb + (size_t)(o0 + r0 + srow) * 1024 + e0 + sc8 * 8, &Wt[buf][r0 * 64]);
    }
  };

  dma(0, 0);

  for (int kt = 0; kt < 16; ++kt) {
    const int cur = kt & 1;
    __syncthreads();  // buffer cur's DMA drained; prev-iter reads of buffer cur done
    if (kt + 1 < 16) dma(cur ^ 1, kt + 1);
#pragma unroll
    for (int kc = 0; kc < 2; ++kc) {
      int ra = w * 16 + l16;
      short8 a = *(const short8*)(&Xt[cur][ra * 64 + ((kc * 4 + quad) ^ (ra & 7)) * 8]);
#pragma unroll
      for (int nf = 0; nf < 8; ++nf) {
        int rb = nf * 16 + l16;
        short8 b = *(const short8*)(&Wt[cur][rb * 64 + ((kc * 4 + quad) ^ (rb & 7)) * 8]);
        acc[nf] = __builtin_amdgcn_mfma_f32_16x16x32_bf16(a, b, acc[nf], 0, 0, 0);
      }
    }
  }

#pragma unroll
  for (int nf = 0; nf < 8; ++nf) {
    float bv = bias[o0 + nf * 16 + l16];
#pragma unroll
    for (int r = 0; r < 4; ++r)
      out[(size_t)(m0 + w * 16 + quad * 4 + r) * 1024 + o0 + nf * 16 + l16] = acc[nf][r] + bv;
  }
}

extern "C" void kernel_launch(void* const* d_in, const int* in_sizes, int n_in,
                              void* d_out, int out_size, void* d_ws, size_t ws_size,
                              hipStream_t stream) {
  const float* values = (const float*)d_in[0];
  const float* keys   = (const float*)d_in[1];
  const float* query  = (const float*)d_in[2];
  const float* Wv     = (const float*)d_in[3];
  const float* Wk     = (const float*)d_in[4];
  const float* Wq     = (const float*)d_in[5];
  const float* Wout   = (const float*)d_in[6];
  const float* bout   = (const float*)d_in[7];
  float* out = (float*)d_out;
  (void)ws_size;

  uint16_t* ws  = (uint16_t*)d_ws;
  uint16_t* qp  = ws;                                // 8 MB bf16 [nh][l][d]
  uint16_t* kp  = ws + (size_t)4194304;              // 8 MB bf16 [nh][l][d]
  uint16_t* vp  = ws + (size_t)8388608;              // 8 MB f16  [nh][d][l]
  uint16_t* wbf = ws + (size_t)12582912;             // 2 MB bf16 Wout
  uint16_t* xat = ws + (size_t)13631488;             // 16 MB bf16 [n,l][e] attention out

  prep_kernel<<<dim3(1024), dim3(256), 0, stream>>>(values, keys, query, Wv, Wk, Wq, Wout,
                                                    qp, kp, vp, wbf);
  flash_kernel<<<dim3(32, 32), dim3(256), 0, stream>>>(qp, kp, vp, xat);
  gemm_xat<<<dim3(64, 8), dim3(256), 0, stream>>>(xat, wbf, bout, out);
}